// Round 18
// baseline (27.750 us; speedup 1.0000x reference)
//
#include <hip/hip_runtime.h>

// Denoiser MLP (2->16, 5x 16->16, 16->2), fp32 in/out, via v_mfma_f32_16x16x16_f16.
// R18: R17 (first win since R8: 32.8->27.7us, from 4-reg D/C tuples ->
// residency) + doubled ILP/MLP and coalesced stores.
//  - 8 independent 16-pt tiles per wave (128 pts/iter): 2 bins x 4 wi_t
//    group-select variants; 32 chains/SIMD at 4 waves; 2 loads in flight.
//  - wo_t output variants (W_out at A-rows {4t,4t+1}): tile t's result lands
//    in lane-group t -> cndmask select -> ALL 64 lanes store one contiguous
//    512B line (2 store instr/body vs 8 masked).
//  - lb(256,4): ~100-reg audit fits 128 budget.
//
// Mapping (verified R3/R17, absmax 7.8e-3):
//   per layer D = A*B, A = weights (16x16), B = activations^T
//   A frag: lane l holds A[i=l&15][k=4*(l>>4)+j], j=0..3
//   B frag: lane l holds B[k=4*(l>>4)+j][n=l&15]
//   D frag: lane l holds D[i=4*(l>>4)+r][n=l&15], r=0..3
//   D layout == B layout -> layers chain in-register, zero cross-lane.
// Input trick: bin = pack2(cvtpk(x,y),0) puts lane l's point at k=4g+{0,1},
// col l&15; wi_t (W_in at k-slots {4t,4t+1}, held by g==t lanes) selects
// group-t lanes' points -> tile t = pts base+16t..16t+15.
// Output trick: wo_t (W_out rows at A-rows {4t,4t+1}) -> tile t's rows 0,1
// land at g==t lanes, regs 0,1; lane (g,nn) selects a_g and stores
// out[base+lane] -- fully coalesced.

typedef _Float16 h4v __attribute__((ext_vector_type(4)));
typedef float f4 __attribute__((ext_vector_type(4)));
typedef float f2 __attribute__((ext_vector_type(2)));
typedef unsigned int u32;
typedef u32 u2v __attribute__((ext_vector_type(2)));

static __device__ __forceinline__ f4 mfma16(h4v a, h4v b, f4 c) {
    return __builtin_amdgcn_mfma_f32_16x16x16f16(a, b, c, 0, 0, 0);
}

static __device__ __forceinline__ u32 cvtpk(float a, float b) {
    return __builtin_bit_cast(u32, __builtin_amdgcn_cvt_pkrtz(a, b));
}

static __device__ __forceinline__ h4v pack2(u32 lo, u32 hi) {
    u2v p = {lo, hi};
    return __builtin_bit_cast(h4v, p);
}

// weight A-fragment: row = given, cols 4g..4g+3
static __device__ __forceinline__ h4v wfrag(const float* row, int g) {
    const f4* r4 = (const f4*)row;
    f4 q = r4[g];
    return pack2(cvtpk(q.x, q.y), cvtpk(q.z, q.w));
}

// relu + cvt of D regs 0-3 -> next layer's B fragment (order-preserving)
static __device__ __forceinline__ h4v cvt_relu4(f4 a) {
    h4v hb = pack2(cvtpk(a[0], a[1]), cvtpk(a[2], a[3]));
    const h4v z = {};
    return __builtin_elementwise_max(hb, z);   // 2x v_pk_max_f16
}

__global__ __launch_bounds__(256, 4) void denoiser_mfma16(
    const f2* __restrict__ x,        // [N] points (x0,x1)
    const float* __restrict__ w_in,  // [16][2]
    const float* __restrict__ w_mid, // [5][16][16]
    const float* __restrict__ w_out, // [2][16]
    f2* __restrict__ out,            // [N] (o0,o1)
    int n)
{
    const int lane = threadIdx.x & 63;
    const int nn   = lane & 15;   // A-row / point-in-tile
    const int g    = lane >> 4;   // k-group / output-row group
    const int wave = threadIdx.x >> 6;

    const h4v hz = {};

    // ---- one-time weight fragments ----
    // input variants: wi_t nonzero only for g==t lanes (k-slots {4t,4t+1})
    u32 wxy = cvtpk(w_in[2 * nn], w_in[2 * nn + 1]);
    h4v wiv = pack2(wxy, 0u);
    h4v wi0 = g == 0 ? wiv : hz;
    h4v wi1 = g == 1 ? wiv : hz;
    h4v wi2 = g == 2 ? wiv : hz;
    h4v wi3 = g == 3 ? wiv : hz;

    h4v wm0 = wfrag(w_mid + 0 * 256 + nn * 16, g);
    h4v wm1 = wfrag(w_mid + 1 * 256 + nn * 16, g);
    h4v wm2 = wfrag(w_mid + 2 * 256 + nn * 16, g);
    h4v wm3 = wfrag(w_mid + 3 * 256 + nn * 16, g);
    h4v wm4 = wfrag(w_mid + 4 * 256 + nn * 16, g);

    // output variants: lane nn holds W_out row (nn&3) if (nn&3)<2; variant
    // t keeps only lanes with nn>>2 == t -> result rows {4t,4t+1} => g==t.
    h4v wofull = (nn & 3) < 2 ? wfrag(w_out + (nn & 3) * 16, g) : hz;
    int tsel = nn >> 2;
    h4v wo0 = tsel == 0 ? wofull : hz;
    h4v wo1 = tsel == 1 ? wofull : hz;
    h4v wo2 = tsel == 2 ? wofull : hz;
    h4v wo3 = tsel == 3 ? wofull : hz;

    // one-time pin: zero C-operand resident, un-rematerializable
    f4 z4 = {};
    asm("" : "+v"(z4));

    const int nchunks = (n + 511) >> 9;     // 512 pts per block-iteration
    const int stride  = gridDim.x;
    const int nm1     = n - 1;

    auto loadx = [&](int c, int half) -> f2 {
        int pi = c * 512 + wave * 128 + half * 64 + lane;
        return x[pi < n ? pi : nm1];
    };

    // select a_g's regs 0,1 by lane group (3 cndmask per component)
    auto selstore = [&](f4 a0, f4 a1, f4 a2, f4 a3) -> f2 {
        float s0 = g < 2 ? (g == 1 ? a1[0] : a0[0]) : (g == 3 ? a3[0] : a2[0]);
        float s1 = g < 2 ? (g == 1 ? a1[1] : a0[1]) : (g == 3 ? a3[1] : a2[1]);
        return (f2){s0, s1};
    };

    int c = blockIdx.x;
    f2 xyA = loadx(c, 0);
    f2 xyB = loadx(c, 1);

    for (; c < nchunks; c += stride) {
        const int cn = c + stride;
        const int cp = cn < nchunks ? cn : c;
        f2 xyA2 = loadx(cp, 0);
        f2 xyB2 = loadx(cp, 1);

        const int base = c * 512 + wave * 128;
        const bool full = (base + 128 <= n);

        // ---- input layer: 2 bins -> 8 tiles ----
        h4v binA = pack2(cvtpk(xyA.x, xyA.y), 0u);
        h4v binB = pack2(cvtpk(xyB.x, xyB.y), 0u);
        f4 a0 = mfma16(wi0, binA, z4);
        f4 a1 = mfma16(wi1, binA, z4);
        f4 a2 = mfma16(wi2, binA, z4);
        f4 a3 = mfma16(wi3, binA, z4);
        f4 a4 = mfma16(wi0, binB, z4);
        f4 a5 = mfma16(wi1, binB, z4);
        f4 a6 = mfma16(wi2, binB, z4);
        f4 a7 = mfma16(wi3, binB, z4);
        h4v b0 = cvt_relu4(a0), b1 = cvt_relu4(a1);
        h4v b2 = cvt_relu4(a2), b3 = cvt_relu4(a3);
        h4v b4 = cvt_relu4(a4), b5 = cvt_relu4(a5);
        h4v b6 = cvt_relu4(a6), b7 = cvt_relu4(a7);

        // ---- 5 mid layers: 8 independent chains ----
        #define MIDLAYER(W)                                        \
            a0 = mfma16(W, b0, z4);  a1 = mfma16(W, b1, z4);       \
            a2 = mfma16(W, b2, z4);  a3 = mfma16(W, b3, z4);       \
            a4 = mfma16(W, b4, z4);  a5 = mfma16(W, b5, z4);       \
            a6 = mfma16(W, b6, z4);  a7 = mfma16(W, b7, z4);       \
            b0 = cvt_relu4(a0);  b1 = cvt_relu4(a1);               \
            b2 = cvt_relu4(a2);  b3 = cvt_relu4(a3);               \
            b4 = cvt_relu4(a4);  b5 = cvt_relu4(a5);               \
            b6 = cvt_relu4(a6);  b7 = cvt_relu4(a7);
        MIDLAYER(wm0)
        MIDLAYER(wm1)
        MIDLAYER(wm2)
        MIDLAYER(wm3)
        MIDLAYER(wm4)
        #undef MIDLAYER

        // ---- output layer: wo_t routes tile t's rows to lane-group t ----
        a0 = mfma16(wo0, b0, z4);
        a1 = mfma16(wo1, b1, z4);
        a2 = mfma16(wo2, b2, z4);
        a3 = mfma16(wo3, b3, z4);
        a4 = mfma16(wo0, b4, z4);
        a5 = mfma16(wo1, b5, z4);
        a6 = mfma16(wo2, b6, z4);
        a7 = mfma16(wo3, b7, z4);

        f2 oA = selstore(a0, a1, a2, a3);   // point base + lane
        f2 oB = selstore(a4, a5, a6, a7);   // point base + 64 + lane

        if (full) {
            out[base + lane]      = oA;     // one 512B contiguous line/wave
            out[base + 64 + lane] = oB;
        } else {
            if (base + lane < n)      out[base + lane]      = oA;
            if (base + 64 + lane < n) out[base + 64 + lane] = oB;
        }

        xyA = xyA2;
        xyB = xyB2;
    }
}

extern "C" void kernel_launch(void* const* d_in, const int* in_sizes, int n_in,
                              void* d_out, int out_size, void* d_ws, size_t ws_size,
                              hipStream_t stream) {
    const float* x     = (const float*)d_in[0];
    const float* w_in  = (const float*)d_in[1];
    const float* w_mid = (const float*)d_in[2];
    const float* w_out = (const float*)d_in[3];

    int n = in_sizes[0] / 2;          // number of points
    int nchunks = (n + 511) / 512;
    int blocks = nchunks < 2048 ? nchunks : 2048;  // persistent

    denoiser_mfma16<<<blocks, 256, 0, stream>>>(
        (const f2*)x, w_in, w_mid, w_out, (f2*)d_out, n);
}